// Round 1
// baseline (6430.139 us; speedup 1.0000x reference)
//
#include <hip/hip_runtime.h>

#define B_ROWS 32768
#define D_NETS 16
#define N_G    1024

// ---------------------------------------------------------------------------
// h-network: 16 independent tiny MLPs (1 -> 64 -> 64 -> 64 -> 64 -> 1).
// grid (B/256, 16); block 256. One thread = one (row, d). Weights for net d
// staged in LDS (uniform broadcast reads); activations in registers.
// ---------------------------------------------------------------------------
__global__ __launch_bounds__(256, 1) void h_net_kernel(
    const float* __restrict__ x,
    const float* __restrict__ hW1, const float* __restrict__ hb1,
    const float* __restrict__ hW2, const float* __restrict__ hb2,
    const float* __restrict__ hW3, const float* __restrict__ hb3,
    const float* __restrict__ hW4, const float* __restrict__ hb4,
    const float* __restrict__ hW5, const float* __restrict__ hb5,
    float* __restrict__ out)
{
    __shared__ float s_w[3 * 4096];   // W2,W3,W4 for this d
    __shared__ float s_w1[64];
    __shared__ float s_b1[64];
    __shared__ float s_bs[3 * 64];    // b2,b3,b4
    __shared__ float s_w5[64];
    __shared__ float s_b5;

    const int d = blockIdx.y;
    const int t = threadIdx.x;

    for (int i = t; i < 4096; i += 256) {
        s_w[i]        = hW2[d * 4096 + i];
        s_w[4096 + i] = hW3[d * 4096 + i];
        s_w[8192 + i] = hW4[d * 4096 + i];
    }
    if (t < 64) {
        s_w1[t]       = hW1[d * 64 + t];
        s_b1[t]       = hb1[d * 64 + t];
        s_bs[t]       = hb2[d * 64 + t];
        s_bs[64 + t]  = hb3[d * 64 + t];
        s_bs[128 + t] = hb4[d * 64 + t];
        s_w5[t]       = hW5[d * 64 + t];
        if (t == 0) s_b5 = hb5[d];
    }
    __syncthreads();

    const int row = blockIdx.x * 256 + t;
    const float sv = x[row * 32 + 16 + d];   // second_half[:, d]

    float ha[64];
    #pragma unroll
    for (int j = 0; j < 64; ++j)
        ha[j] = fmaxf(fmaf(sv, s_w1[j], s_b1[j]), 0.0f);

    #pragma unroll 1
    for (int L = 0; L < 3; ++L) {
        const float* W  = &s_w[L * 4096];
        const float* bb = &s_bs[L * 64];
        float hn[64];
        #pragma unroll
        for (int g = 0; g < 64; ++g) {
            float a0 = bb[g], a1 = 0.f, a2 = 0.f, a3 = 0.f;
            #pragma unroll
            for (int h4 = 0; h4 < 16; ++h4) {
                float4 wv = *reinterpret_cast<const float4*>(&W[g * 64 + h4 * 4]);
                a0 = fmaf(ha[h4 * 4 + 0], wv.x, a0);
                a1 = fmaf(ha[h4 * 4 + 1], wv.y, a1);
                a2 = fmaf(ha[h4 * 4 + 2], wv.z, a2);
                a3 = fmaf(ha[h4 * 4 + 3], wv.w, a3);
            }
            hn[g] = fmaxf((a0 + a1) + (a2 + a3), 0.0f);
        }
        #pragma unroll
        for (int j = 0; j < 64; ++j) ha[j] = hn[j];
    }

    float o0 = 0.f, o1 = 0.f, o2 = 0.f, o3 = 0.f;
    #pragma unroll
    for (int h4 = 0; h4 < 16; ++h4) {
        o0 = fmaf(ha[h4 * 4 + 0], s_w5[h4 * 4 + 0], o0);
        o1 = fmaf(ha[h4 * 4 + 1], s_w5[h4 * 4 + 1], o1);
        o2 = fmaf(ha[h4 * 4 + 2], s_w5[h4 * 4 + 2], o2);
        o3 = fmaf(ha[h4 * 4 + 3], s_w5[h4 * 4 + 3], o3);
    }
    out[row * D_NETS + d] = (o0 + o1) + (o2 + o3) + s_b5;
}

// ---------------------------------------------------------------------------
// g-network: fused 16 -> 1024 -> 1024 -> 1024 -> 1024 -> 1.
// grid B/16; block 256 (4 waves). Activations (16 rows x 1024) double-buffered
// in LDS; W streamed in (32k x 256n) tiles through a 32 KiB XOR-swizzled LDS
// buffer with register prefetch of the next tile during compute.
// Thread microtile: 4 rows x 4 cols; wave w owns rows 4w..4w+3; lane l owns
// cols n = nt*256 + 64*j + l (j=0..3).
// ---------------------------------------------------------------------------
__global__ __launch_bounds__(256, 1) void g_net_kernel(
    const float* __restrict__ x,
    const float* __restrict__ gW1, const float* __restrict__ gb1,
    const float* __restrict__ gW2, const float* __restrict__ gb2,
    const float* __restrict__ gW3, const float* __restrict__ gb3,
    const float* __restrict__ gW4, const float* __restrict__ gb4,
    const float* __restrict__ gW5, const float* __restrict__ gb5,
    float* __restrict__ out)
{
    __shared__ float AB[2 * 16 * 1024];   // 128 KiB activation double buffer
    __shared__ float WT[32 * 256];        // 32 KiB W tile, k-major, XOR swizzle

    const int t    = threadIdx.x;
    const int l    = t & 63;
    const int rg   = t >> 6;              // wave id = row group
    const int row0 = blockIdx.x * 16;

    // ---- stage x[:, :16] into WT area (temporarily) ----
    if (t < 64) {
        const int r = t >> 2, c = t & 3;
        float4 v = *reinterpret_cast<const float4*>(&x[(row0 + r) * 32 + c * 4]);
        *reinterpret_cast<float4*>(&WT[r * 16 + c * 4]) = v;
    }
    __syncthreads();

    // ---- layer 1 (K = 16) -> AB[0 .. 16K) ----
    #pragma unroll
    for (int jo = 0; jo < 4; ++jo) {
        float acc1[4][4];   // [r][ji]
        #pragma unroll
        for (int ji = 0; ji < 4; ++ji) {
            const float b = gb1[jo * 256 + 64 * ji + l];
            #pragma unroll
            for (int r = 0; r < 4; ++r) acc1[r][ji] = b;
        }
        #pragma unroll
        for (int kc = 0; kc < 4; ++kc) {
            float4 xv[4];
            #pragma unroll
            for (int r = 0; r < 4; ++r)
                xv[r] = *reinterpret_cast<const float4*>(&WT[(rg * 4 + r) * 16 + kc * 4]);
            #pragma unroll
            for (int ji = 0; ji < 4; ++ji) {
                float4 wv = *reinterpret_cast<const float4*>(
                    &gW1[(jo * 256 + 64 * ji + l) * 16 + kc * 4]);
                #pragma unroll
                for (int r = 0; r < 4; ++r) {
                    acc1[r][ji] = fmaf(xv[r].x, wv.x, acc1[r][ji]);
                    acc1[r][ji] = fmaf(xv[r].y, wv.y, acc1[r][ji]);
                    acc1[r][ji] = fmaf(xv[r].z, wv.z, acc1[r][ji]);
                    acc1[r][ji] = fmaf(xv[r].w, wv.w, acc1[r][ji]);
                }
            }
        }
        #pragma unroll
        for (int r = 0; r < 4; ++r)
            #pragma unroll
            for (int ji = 0; ji < 4; ++ji)
                AB[(rg * 4 + r) * 1024 + jo * 256 + 64 * ji + l] =
                    fmaxf(acc1[r][ji], 0.0f);
    }

    // ---- layers 2..4 ----
    const int np  = t >> 3;          // 0..31 : n-row within tile (low 5 bits)
    const int kc8 = (t & 7) * 4;     // 0..28 : k chunk

    float4 pv[8];
    auto wbase = [&](int s) -> const float* {
        const int Lz = s >> 7;
        return (Lz == 0) ? gW2 : ((Lz == 1) ? gW3 : gW4);
    };
    auto prefetch = [&](int s) {
        const float* W = wbase(s);
        const int nt = (s >> 5) & 3;
        const int kt = s & 31;
        const int n0 = nt * 256, k0 = kt * 32;
        #pragma unroll
        for (int jj = 0; jj < 8; ++jj)
            pv[jj] = *reinterpret_cast<const float4*>(
                &W[(size_t)(n0 + np + 32 * jj) * 1024 + k0 + kc8]);
    };
    prefetch(0);

    int so = 0;           // src activation offset in AB
    float acc[4][4];

    #pragma unroll 1
    for (int s = 0; s < 384; ++s) {
        const int kt = s & 31;
        const int nt = (s >> 5) & 3;

        __syncthreads();              // previous stage done consuming WT
        #pragma unroll
        for (int jj = 0; jj < 8; ++jj) {
            WT[(kc8 + 0) * 256 + (np ^ (kc8 + 0)) + 32 * jj] = pv[jj].x;
            WT[(kc8 + 1) * 256 + (np ^ (kc8 + 1)) + 32 * jj] = pv[jj].y;
            WT[(kc8 + 2) * 256 + (np ^ (kc8 + 2)) + 32 * jj] = pv[jj].z;
            WT[(kc8 + 3) * 256 + (np ^ (kc8 + 3)) + 32 * jj] = pv[jj].w;
        }
        __syncthreads();              // WT ready
        if (s + 1 < 384) prefetch(s + 1);   // hide next tile's load latency

        if (kt == 0) {
            const int Lz = s >> 7;
            const float* gbL = (Lz == 0) ? gb2 : ((Lz == 1) ? gb3 : gb4);
            #pragma unroll
            for (int j = 0; j < 4; ++j) {
                const float b = gbL[nt * 256 + 64 * j + l];
                #pragma unroll
                for (int r = 0; r < 4; ++r) acc[r][j] = b;
            }
        }

        const int k0 = kt * 32;
        #pragma unroll
        for (int kk4 = 0; kk4 < 8; ++kk4) {
            float4 av[4];
            #pragma unroll
            for (int r = 0; r < 4; ++r)
                av[r] = *reinterpret_cast<const float4*>(
                    &AB[so + (rg * 4 + r) * 1024 + k0 + kk4 * 4]);

#define G_STEP(ii, comp)                                              \
            {                                                         \
                const int kk = kk4 * 4 + ii;                          \
                const int cb = kk * 256 + (l ^ kk);                   \
                const float w0 = WT[cb];                              \
                const float w1 = WT[cb + 64];                         \
                const float w2 = WT[cb + 128];                        \
                const float w3 = WT[cb + 192];                        \
                _Pragma("unroll")                                     \
                for (int r = 0; r < 4; ++r) {                         \
                    const float a = av[r].comp;                       \
                    acc[r][0] = fmaf(a, w0, acc[r][0]);               \
                    acc[r][1] = fmaf(a, w1, acc[r][1]);               \
                    acc[r][2] = fmaf(a, w2, acc[r][2]);               \
                    acc[r][3] = fmaf(a, w3, acc[r][3]);               \
                }                                                     \
            }
            G_STEP(0, x)
            G_STEP(1, y)
            G_STEP(2, z)
            G_STEP(3, w)
#undef G_STEP
        }

        if (kt == 31) {
            const int dsto = so ^ 16384;
            #pragma unroll
            for (int r = 0; r < 4; ++r)
                #pragma unroll
                for (int j = 0; j < 4; ++j)
                    AB[dsto + (rg * 4 + r) * 1024 + nt * 256 + 64 * j + l] =
                        fmaxf(acc[r][j], 0.0f);
            if (nt == 3) so ^= 16384;   // layer finished: swap act buffers
        }
    }

    // ---- layer 5: out_g[row] = act4 . gW5 + gb5 ----
    __syncthreads();
    {
        const int r = t >> 4;    // 0..15 row
        const int c = t & 15;    // 0..15 k-chunk of 64
        float p0 = 0.f, p1 = 0.f, p2 = 0.f, p3 = 0.f;
        #pragma unroll
        for (int q = 0; q < 16; ++q) {
            float4 a = *reinterpret_cast<const float4*>(
                &AB[so + r * 1024 + c * 64 + q * 4]);
            float4 w = *reinterpret_cast<const float4*>(&gW5[c * 64 + q * 4]);
            p0 = fmaf(a.x, w.x, p0);
            p1 = fmaf(a.y, w.y, p1);
            p2 = fmaf(a.z, w.z, p2);
            p3 = fmaf(a.w, w.w, p3);
        }
        WT[t] = (p0 + p1) + (p2 + p3);   // t == r*16 + c
    }
    __syncthreads();
    if (t < 16) {
        float sum = gb5[0];
        #pragma unroll
        for (int c = 0; c < 16; ++c) sum += WT[t * 16 + c];
        out[B_ROWS * D_NETS + row0 + t] = sum;
    }
}

extern "C" void kernel_launch(void* const* d_in, const int* in_sizes, int n_in,
                              void* d_out, int out_size, void* d_ws, size_t ws_size,
                              hipStream_t stream) {
    (void)in_sizes; (void)n_in; (void)out_size; (void)d_ws; (void)ws_size;

    const float* x   = (const float*)d_in[0];
    const float* hW1 = (const float*)d_in[1];
    const float* hb1 = (const float*)d_in[2];
    const float* hW2 = (const float*)d_in[3];
    const float* hb2 = (const float*)d_in[4];
    const float* hW3 = (const float*)d_in[5];
    const float* hb3 = (const float*)d_in[6];
    const float* hW4 = (const float*)d_in[7];
    const float* hb4 = (const float*)d_in[8];
    const float* hW5 = (const float*)d_in[9];
    const float* hb5 = (const float*)d_in[10];
    const float* gW1 = (const float*)d_in[11];
    const float* gb1 = (const float*)d_in[12];
    const float* gW2 = (const float*)d_in[13];
    const float* gb2 = (const float*)d_in[14];
    const float* gW3 = (const float*)d_in[15];
    const float* gb3 = (const float*)d_in[16];
    const float* gW4 = (const float*)d_in[17];
    const float* gb4 = (const float*)d_in[18];
    const float* gW5 = (const float*)d_in[19];
    const float* gb5 = (const float*)d_in[20];
    float* out = (float*)d_out;

    dim3 gh(B_ROWS / 256, D_NETS);
    h_net_kernel<<<gh, 256, 0, stream>>>(x, hW1, hb1, hW2, hb2, hW3, hb3,
                                         hW4, hb4, hW5, hb5, out);
    g_net_kernel<<<B_ROWS / 16, 256, 0, stream>>>(x, gW1, gb1, gW2, gb2,
                                                  gW3, gb3, gW4, gb4,
                                                  gW5, gb5, out);
}

// Round 2
// 1873.928 us; speedup vs baseline: 3.4314x; 3.4314x over previous
//
#include <hip/hip_runtime.h>

#define B_ROWS 32768
#define D_NETS 16
#define NW     1024
#define MW     1048576   // 1024*1024

typedef __attribute__((ext_vector_type(8)))  short bf16x8;
typedef __attribute__((ext_vector_type(16))) float f32x16;

__device__ __forceinline__ ushort bf16_rne(float f) {
    unsigned u = __float_as_uint(f);
    unsigned r = u + 0x7FFFu + ((u >> 16) & 1u);
    return (ushort)(r >> 16);
}
__device__ __forceinline__ float bf16_to_f(ushort h) {
    return __uint_as_float(((unsigned)h) << 16);
}

// ---------------------------------------------------------------------------
// prep: split gW2/gW3/gW4 (1024x1024) and gW1 (1024x16) into bf16 hi/lo in ws.
// ws layout (ushort units): W2h@0, W2l@1M, W3h@2M, W3l@3M, W4h@4M, W4l@5M,
//                           W1h@6M, W1l@6M+16384
// ---------------------------------------------------------------------------
__global__ void split_weights(const float* __restrict__ gW1,
                              const float* __restrict__ gW2,
                              const float* __restrict__ gW3,
                              const float* __restrict__ gW4,
                              ushort* __restrict__ ws) {
    int i = blockIdx.x * 256 + threadIdx.x;
    float w; int hoff, loff, idx;
    if (i < MW)            { idx = i;          w = gW2[idx]; hoff = 0;      loff = MW;     }
    else if (i < 2 * MW)   { idx = i - MW;     w = gW3[idx]; hoff = 2 * MW; loff = 3 * MW; }
    else if (i < 3 * MW)   { idx = i - 2 * MW; w = gW4[idx]; hoff = 4 * MW; loff = 5 * MW; }
    else                   { idx = i - 3 * MW; if (idx >= 16384) return;
                             w = gW1[idx]; hoff = 6 * MW; loff = 6 * MW + 16384; }
    ushort h = bf16_rne(w);
    ws[hoff + idx] = h;
    ws[loff + idx] = bf16_rne(w - bf16_to_f(h));
}

// ---------------------------------------------------------------------------
// h-network: unchanged from round 1 (passed; ~small share of runtime).
// ---------------------------------------------------------------------------
__global__ __launch_bounds__(256, 1) void h_net_kernel(
    const float* __restrict__ x,
    const float* __restrict__ hW1, const float* __restrict__ hb1,
    const float* __restrict__ hW2, const float* __restrict__ hb2,
    const float* __restrict__ hW3, const float* __restrict__ hb3,
    const float* __restrict__ hW4, const float* __restrict__ hb4,
    const float* __restrict__ hW5, const float* __restrict__ hb5,
    float* __restrict__ out)
{
    __shared__ float s_w[3 * 4096];
    __shared__ float s_w1[64];
    __shared__ float s_b1[64];
    __shared__ float s_bs[3 * 64];
    __shared__ float s_w5[64];
    __shared__ float s_b5;

    const int d = blockIdx.y;
    const int t = threadIdx.x;

    for (int i = t; i < 4096; i += 256) {
        s_w[i]        = hW2[d * 4096 + i];
        s_w[4096 + i] = hW3[d * 4096 + i];
        s_w[8192 + i] = hW4[d * 4096 + i];
    }
    if (t < 64) {
        s_w1[t]       = hW1[d * 64 + t];
        s_b1[t]       = hb1[d * 64 + t];
        s_bs[t]       = hb2[d * 64 + t];
        s_bs[64 + t]  = hb3[d * 64 + t];
        s_bs[128 + t] = hb4[d * 64 + t];
        s_w5[t]       = hW5[d * 64 + t];
        if (t == 0) s_b5 = hb5[d];
    }
    __syncthreads();

    const int row = blockIdx.x * 256 + t;
    const float sv = x[row * 32 + 16 + d];

    float ha[64];
    #pragma unroll
    for (int j = 0; j < 64; ++j)
        ha[j] = fmaxf(fmaf(sv, s_w1[j], s_b1[j]), 0.0f);

    #pragma unroll 1
    for (int L = 0; L < 3; ++L) {
        const float* W  = &s_w[L * 4096];
        const float* bb = &s_bs[L * 64];
        float hn[64];
        #pragma unroll
        for (int g = 0; g < 64; ++g) {
            float a0 = bb[g], a1 = 0.f, a2 = 0.f, a3 = 0.f;
            #pragma unroll
            for (int h4 = 0; h4 < 16; ++h4) {
                float4 wv = *reinterpret_cast<const float4*>(&W[g * 64 + h4 * 4]);
                a0 = fmaf(ha[h4 * 4 + 0], wv.x, a0);
                a1 = fmaf(ha[h4 * 4 + 1], wv.y, a1);
                a2 = fmaf(ha[h4 * 4 + 2], wv.z, a2);
                a3 = fmaf(ha[h4 * 4 + 3], wv.w, a3);
            }
            hn[g] = fmaxf((a0 + a1) + (a2 + a3), 0.0f);
        }
        #pragma unroll
        for (int j = 0; j < 64; ++j) ha[j] = hn[j];
    }

    float o0 = 0.f, o1 = 0.f, o2 = 0.f, o3 = 0.f;
    #pragma unroll
    for (int h4 = 0; h4 < 16; ++h4) {
        o0 = fmaf(ha[h4 * 4 + 0], s_w5[h4 * 4 + 0], o0);
        o1 = fmaf(ha[h4 * 4 + 1], s_w5[h4 * 4 + 1], o1);
        o2 = fmaf(ha[h4 * 4 + 2], s_w5[h4 * 4 + 2], o2);
        o3 = fmaf(ha[h4 * 4 + 3], s_w5[h4 * 4 + 3], o3);
    }
    out[row * D_NETS + d] = (o0 + o1) + (o2 + o3) + s_b5;
}

// ---------------------------------------------------------------------------
// g-network via split-bf16 MFMA (32x32x16), fully fused.
// grid B/32 = 1024 blocks; 512 threads = 8 waves; wave w owns cols
// [w*128, w*128+128). Acts (32 x 1024) in LDS as bf16 hi/lo with XOR swizzle
// (ushort idx ^= (row&7)<<3). Whole layer accumulated in regs (64 f32/thread),
// C = Ah*Wh + Al*Wh + Ah*Wl (fp32 MFMA accumulate). W frags stream from
// global (L2-resident: 4 MB/layer), software-pipelined 2-deep.
// ---------------------------------------------------------------------------
__global__ __launch_bounds__(512, 2) void g_net_mfma(
    const float* __restrict__ x,
    const ushort* __restrict__ ws,
    const float* __restrict__ gb1, const float* __restrict__ gb2,
    const float* __restrict__ gb3, const float* __restrict__ gb4,
    const float* __restrict__ gW5, const float* __restrict__ gb5,
    float* __restrict__ out)
{
    __shared__ ushort s_Ah[32 * 1024];   // 64 KiB
    __shared__ ushort s_Al[32 * 1024];   // 64 KiB
    __shared__ ushort s_xh[32 * 16];
    __shared__ ushort s_xl[32 * 16];
    __shared__ float  s_red[512];

    const int t    = threadIdx.x;
    const int l    = t & 63;
    const int wv   = t >> 6;        // wave 0..7
    const int row0 = blockIdx.x * 32;
    const int n0   = wv * 128;      // wave's 128-col slice
    const int lr   = l & 31;        // lane row/col index within 32
    const int lk   = l >> 5;        // k half
    const int lk8  = lk * 8;
    const int akey = (lr & 7) << 3; // swizzle key for A reads (ushort units)

    // ---- stage split x[:, :16] ----
    {
        const int r = t >> 4, c = t & 15;
        float v = x[(row0 + r) * 32 + c];
        ushort h = bf16_rne(v);
        s_xh[r * 16 + c] = h;
        s_xl[r * 16 + c] = bf16_rne(v - bf16_to_f(h));
    }
    __syncthreads();

    f32x16 acc[4];

    // ---- layer 1 (K = 16, one k-step) ----
    {
        const ushort* W1h = ws + 6 * MW;
        const ushort* W1l = W1h + 16384;
        bf16x8 ah = *(const bf16x8*)&s_xh[lr * 16 + lk8];
        bf16x8 al = *(const bf16x8*)&s_xl[lr * 16 + lk8];
        #pragma unroll
        for (int nt = 0; nt < 4; ++nt) {
            const int n = n0 + nt * 32 + lr;
            bf16x8 bh = *(const bf16x8*)&W1h[n * 16 + lk8];
            bf16x8 bl = *(const bf16x8*)&W1l[n * 16 + lk8];
            const float bv = gb1[n];
            f32x16 a;
            #pragma unroll
            for (int r = 0; r < 16; ++r) a[r] = bv;
            a = __builtin_amdgcn_mfma_f32_32x32x16_bf16(ah, bh, a, 0, 0, 0);
            a = __builtin_amdgcn_mfma_f32_32x32x16_bf16(al, bh, a, 0, 0, 0);
            a = __builtin_amdgcn_mfma_f32_32x32x16_bf16(ah, bl, a, 0, 0, 0);
            acc[nt] = a;
        }
        // writeback relu + split
        #pragma unroll
        for (int nt = 0; nt < 4; ++nt) {
            const int nc = n0 + nt * 32 + lr;
            #pragma unroll
            for (int r = 0; r < 16; ++r) {
                const int row = (r & 3) + 8 * (r >> 2) + 4 * lk;
                float v2 = fmaxf(acc[nt][r], 0.0f);
                ushort h = bf16_rne(v2);
                const int idx = row * 1024 + (nc ^ ((row & 7) << 3));
                s_Ah[idx] = h;
                s_Al[idx] = bf16_rne(v2 - bf16_to_f(h));
            }
        }
    }
    __syncthreads();

    // ---- layers 2..4 ----
    int wo[4];
    #pragma unroll
    for (int nt = 0; nt < 4; ++nt)
        wo[nt] = (n0 + nt * 32 + lr) * 1024 + lk8;
    const int abase = lr * 1024;

#define LOADK(ks, BH, BL, AH, AL)                                       \
    {                                                                   \
        const int _ko = (ks) * 16;                                      \
        _Pragma("unroll")                                               \
        for (int nt = 0; nt < 4; ++nt) {                                \
            BH[nt] = *(const bf16x8*)&Wh[wo[nt] + _ko];                 \
            BL[nt] = *(const bf16x8*)&Wl[wo[nt] + _ko];                 \
        }                                                               \
        const int _ai = abase + ((_ko + lk8) ^ akey);                   \
        AH = *(const bf16x8*)&s_Ah[_ai];                                \
        AL = *(const bf16x8*)&s_Al[_ai];                                \
    }

#define DOMFMA(BH, BL, AH, AL)                                          \
    {                                                                   \
        _Pragma("unroll")                                               \
        for (int nt = 0; nt < 4; ++nt) {                                \
            acc[nt] = __builtin_amdgcn_mfma_f32_32x32x16_bf16(AH, BH[nt], acc[nt], 0, 0, 0); \
            acc[nt] = __builtin_amdgcn_mfma_f32_32x32x16_bf16(AL, BH[nt], acc[nt], 0, 0, 0); \
            acc[nt] = __builtin_amdgcn_mfma_f32_32x32x16_bf16(AH, BL[nt], acc[nt], 0, 0, 0); \
        }                                                               \
    }

    #pragma unroll 1
    for (int L = 0; L < 3; ++L) {
        const ushort* Wh = ws + (2 * L) * MW;
        const ushort* Wl = ws + (2 * L + 1) * MW;
        const float* gbL = (L == 0) ? gb2 : ((L == 1) ? gb3 : gb4);

        #pragma unroll
        for (int nt = 0; nt < 4; ++nt) {
            const float bv = gbL[n0 + nt * 32 + lr];
            #pragma unroll
            for (int r = 0; r < 16; ++r) acc[nt][r] = bv;
        }

        bf16x8 Bh0[4], Bl0[4], Bh1[4], Bl1[4];
        bf16x8 Ah0, Al0, Ah1, Al1;

        LOADK(0, Bh0, Bl0, Ah0, Al0);
        #pragma unroll 1
        for (int ks = 0; ks < 64; ks += 2) {
            if (ks + 1 < 64) LOADK(ks + 1, Bh1, Bl1, Ah1, Al1);
            DOMFMA(Bh0, Bl0, Ah0, Al0);
            if (ks + 2 < 64) LOADK(ks + 2, Bh0, Bl0, Ah0, Al0);
            DOMFMA(Bh1, Bl1, Ah1, Al1);
        }

        __syncthreads();   // everyone done READING s_Ah/s_Al
        #pragma unroll
        for (int nt = 0; nt < 4; ++nt) {
            const int nc = n0 + nt * 32 + lr;
            #pragma unroll
            for (int r = 0; r < 16; ++r) {
                const int row = (r & 3) + 8 * (r >> 2) + 4 * lk;
                float v2 = fmaxf(acc[nt][r], 0.0f);
                ushort h = bf16_rne(v2);
                const int idx = row * 1024 + (nc ^ ((row & 7) << 3));
                s_Ah[idx] = h;
                s_Al[idx] = bf16_rne(v2 - bf16_to_f(h));
            }
        }
        __syncthreads();   // acts ready for next layer
    }
#undef LOADK
#undef DOMFMA

    // ---- layer 5: out_g[row] = act . gW5 + gb5 ----
    {
        const int r = t >> 4;     // 0..31
        const int c = t & 15;     // 0..15, 64 k each
        const int rkey = (r & 7) << 3;
        float s = 0.0f;
        #pragma unroll 8
        for (int q = 0; q < 64; ++q) {
            const int k = c * 64 + q;
            const int idx = r * 1024 + (k ^ rkey);
            float a = bf16_to_f(s_Ah[idx]) + bf16_to_f(s_Al[idx]);
            s = fmaf(a, gW5[k], s);
        }
        s_red[t] = s;
    }
    __syncthreads();
    if (t < 32) {
        float sum = gb5[0];
        #pragma unroll
        for (int c = 0; c < 16; ++c) sum += s_red[t * 16 + c];
        out[B_ROWS * D_NETS + row0 + t] = sum;
    }
}

extern "C" void kernel_launch(void* const* d_in, const int* in_sizes, int n_in,
                              void* d_out, int out_size, void* d_ws, size_t ws_size,
                              hipStream_t stream) {
    (void)in_sizes; (void)n_in; (void)out_size; (void)ws_size;

    const float* x   = (const float*)d_in[0];
    const float* hW1 = (const float*)d_in[1];
    const float* hb1 = (const float*)d_in[2];
    const float* hW2 = (const float*)d_in[3];
    const float* hb2 = (const float*)d_in[4];
    const float* hW3 = (const float*)d_in[5];
    const float* hb3 = (const float*)d_in[6];
    const float* hW4 = (const float*)d_in[7];
    const float* hb4 = (const float*)d_in[8];
    const float* hW5 = (const float*)d_in[9];
    const float* hb5 = (const float*)d_in[10];
    const float* gW1 = (const float*)d_in[11];
    const float* gb1 = (const float*)d_in[12];
    const float* gW2 = (const float*)d_in[13];
    const float* gb2 = (const float*)d_in[14];
    const float* gW3 = (const float*)d_in[15];
    const float* gb3 = (const float*)d_in[16];
    const float* gW4 = (const float*)d_in[17];
    const float* gb4 = (const float*)d_in[18];
    const float* gW5 = (const float*)d_in[19];
    const float* gb5 = (const float*)d_in[20];
    float* out = (float*)d_out;
    ushort* wsp = (ushort*)d_ws;

    split_weights<<<(3 * MW + 16384 + 255) / 256, 256, 0, stream>>>(gW1, gW2, gW3, gW4, wsp);

    dim3 gh(B_ROWS / 256, D_NETS);
    h_net_kernel<<<gh, 256, 0, stream>>>(x, hW1, hb1, hW2, hb2, hW3, hb3,
                                         hW4, hb4, hW5, hb5, out);

    g_net_mfma<<<B_ROWS / 32, 512, 0, stream>>>(x, wsp, gb1, gb2, gb3, gb4,
                                                gW5, gb5, out);
}